// Round 3
// baseline (118.500 us; speedup 1.0000x reference)
//
#include <hip/hip_runtime.h>
#include <math.h>

#define NSEG 20001      // I_DIM + 1 segments / items
#define EMB  128
#define NE   640000

#define SCALE_BLOCKS ((NSEG + 15) / 16)          // 1251
#define BOUNDS_BLOCKS (NE / 256)                 // 2500 (exact)

__device__ __forceinline__ float dot4(float4 a, float4 b) {
    return a.x*b.x + a.y*b.y + a.z*b.z + a.w*b.w;
}

#define FMA4(acc, s, b) { acc.x += (s)*(b).x; acc.y += (s)*(b).y; acc.z += (s)*(b).z; acc.w += (s)*(b).w; }

__device__ __forceinline__ unsigned short f2bf(float x) {
    unsigned u = __float_as_uint(x);
    unsigned r = (u + 0x7fffu + ((u >> 16) & 1u)) >> 16;   // round-nearest-even
    return (unsigned short)r;
}

// Fused prep: blocks [0, SCALE_BLOCKS): item_scaled(bf16 tab) + a_src/a_dst.
//             blocks [SCALE_BLOCKS, +BOUNDS_BLOCKS): segment bounds + dst compaction.
__global__ __launch_bounds__(256) void prep_kernel(
    const float* __restrict__ emb, const float* __restrict__ W,
    const float* __restrict__ bsc, const float* __restrict__ Watt,
    const int* __restrict__ edge,
    unsigned short* __restrict__ tab,       // bf16 item_scaled, NSEG x EMB
    float* __restrict__ a_src, float* __restrict__ a_dst,
    int* __restrict__ seg_start, int* __restrict__ dst)
{
    const int tid = threadIdx.x;
    if (blockIdx.x >= SCALE_BLOCKS) {
        // ---- bounds + dst-compaction branch ----
        int e = (blockIdx.x - SCALE_BLOCKS) * 256 + tid;
        int2 p = ((const int2*)edge)[e];            // (src, dst) coalesced 8B
        dst[e] = p.y;
        int sp = __shfl_up(p.x, 1);
        if ((tid & 63) == 0) sp = (e == 0) ? -1 : edge[2*e - 2];
        for (int t = sp + 1; t <= p.x; ++t) seg_start[t] = e;
        if (e == NE - 1) {
            for (int t = p.x + 1; t <= NSEG; ++t) seg_start[t] = NE;
        }
        return;
    }

    // ---- scale branch: 16 rows/block; thread = (col-group cg: 4 cols) x (2 rows) ----
    __shared__ float emb_s[16 * EMB];   // 8 KB
    const int r0 = blockIdx.x * 16;

    const float4* embg4 = (const float4*)emb;
    float4* es4 = (float4*)emb_s;
    const int gmax = NSEG * 32 - 1;
    #pragma unroll
    for (int j = 0; j < 2; ++j) {
        int idx = tid + j * 256;
        int g = r0 * 32 + idx;
        es4[idx] = embg4[g <= gmax ? g : gmax];
    }
    __syncthreads();

    const int cg = tid & 31;
    const int rb = (tid >> 5) * 2;

    float4 acc0 = {0.f,0.f,0.f,0.f};
    float4 acc1 = {0.f,0.f,0.f,0.f};
    const float4* Wg4 = (const float4*)W;

    for (int k = 0; k < EMB; k += 4) {
        float4 b0 = Wg4[(k+0)*32 + cg];
        float4 b1 = Wg4[(k+1)*32 + cg];
        float4 b2 = Wg4[(k+2)*32 + cg];
        float4 b3 = Wg4[(k+3)*32 + cg];
        float4 a0 = *(const float4*)&emb_s[(rb+0)*EMB + k];
        float4 a1 = *(const float4*)&emb_s[(rb+1)*EMB + k];
        FMA4(acc0, a0.x, b0); FMA4(acc0, a0.y, b1); FMA4(acc0, a0.z, b2); FMA4(acc0, a0.w, b3);
        FMA4(acc1, a1.x, b0); FMA4(acc1, a1.y, b1); FMA4(acc1, a1.z, b2); FMA4(acc1, a1.w, b3);
    }

    float4 bs = *(const float4*)&bsc[cg*4];
    acc0.x += bs.x; acc0.y += bs.y; acc0.z += bs.z; acc0.w += bs.w;
    acc1.x += bs.x; acc1.y += bs.y; acc1.z += bs.z; acc1.w += bs.w;

    const int row0 = r0 + rb;
    const int row1 = row0 + 1;
    if (row0 < NSEG) {
        ushort4 p = { f2bf(acc0.x), f2bf(acc0.y), f2bf(acc0.z), f2bf(acc0.w) };
        *(ushort4*)&tab[row0*EMB + cg*4] = p;
    }
    if (row1 < NSEG) {
        ushort4 p = { f2bf(acc1.x), f2bf(acc1.y), f2bf(acc1.z), f2bf(acc1.w) };
        *(ushort4*)&tab[row1*EMB + cg*4] = p;
    }

    float4 ws = *(const float4*)&Watt[cg*4];
    float4 wd = *(const float4*)&Watt[EMB + cg*4];
    float p0s = dot4(acc0, ws), p0d = dot4(acc0, wd);
    float p1s = dot4(acc1, ws), p1d = dot4(acc1, wd);
    #pragma unroll
    for (int off = 16; off >= 1; off >>= 1) {
        p0s += __shfl_xor(p0s, off);
        p0d += __shfl_xor(p0d, off);
        p1s += __shfl_xor(p1s, off);
        p1d += __shfl_xor(p1d, off);
    }
    if ((tid & 31) == 0) {
        if (row0 < NSEG) { a_src[row0] = p0s; a_dst[row0] = p0d; }
        if (row1 < NSEG) { a_src[row1] = p1s; a_dst[row1] = p1d; }
    }
}

__device__ __forceinline__ float bf_lo(unsigned u) { return __uint_as_float(u << 16); }
__device__ __forceinline__ float bf_hi(unsigned u) { return __uint_as_float(u & 0xffff0000u); }

// agg: one wave per segment. Quadrant-parallel gather: per iteration the wave
// processes 4 edges; quadrant q (lanes 16q..16q+15) handles edge j+q, each lane
// loading one dwordx4 (8 bf16 features) of tab[dst]. Lane accumulates features
// [(lane&15)*8, +8); quadrants xor-reduced in the epilogue.
__global__ __launch_bounds__(256) void agg_kernel(
    const int* __restrict__ dst, const float* __restrict__ a_src,
    const float* __restrict__ a_dst, const float* __restrict__ b_att,
    const int* __restrict__ seg_start, const unsigned char* __restrict__ tabb,
    float* __restrict__ out)
{
    const int wid = blockIdx.x * 4 + (threadIdx.x >> 6);
    if (wid >= NSEG) return;                 // wave-uniform exit
    const int lane = threadIdx.x & 63;
    const int quad = lane >> 4;
    const int qoff = (lane & 15) * 16;       // byte offset within a 256B row

    const int s0 = seg_start[wid];
    const int s1 = seg_start[wid + 1];
    const float aS = a_src[wid] + b_att[0];

    float c0=0.f,c1=0.f,c2=0.f,c3=0.f,c4=0.f,c5=0.f,c6=0.f,c7=0.f;
    float ssum = 0.f;

    for (int cb = s0; cb < s1; cb += 64) {
        int n = s1 - cb; if (n > 64) n = 64;
        int e = cb + lane;
        int dmine = 0; float sc = 0.f;
        if (lane < n) {
            dmine = dst[e];                       // coalesced
            float att = aS + a_dst[dmine];
            att = att > 0.f ? att : 0.2f * att;   // leaky_relu 0.2
            sc  = expf(att - 1.f);
        }
        ssum += sc;

        #pragma unroll 4
        for (int j = 0; j < n; j += 4) {
            float w = __shfl(sc, j + quad, 64);
            int   d = __shfl(dmine, j + quad, 64);
            uint4 u = *(const uint4*)(tabb + ((size_t)(unsigned)((d << 8) + qoff)));
            c0 += w * bf_lo(u.x); c1 += w * bf_hi(u.x);
            c2 += w * bf_lo(u.y); c3 += w * bf_hi(u.y);
            c4 += w * bf_lo(u.z); c5 += w * bf_hi(u.z);
            c6 += w * bf_lo(u.w); c7 += w * bf_hi(u.w);
        }
    }

    // sum scores across all 64 lanes
    #pragma unroll
    for (int off = 32; off >= 1; off >>= 1) ssum += __shfl_xor(ssum, off);

    // reduce the 4 quadrants (lanes with equal lane&15 share a feature block)
    #pragma unroll
    for (int off = 16; off <= 32; off <<= 1) {
        c0 += __shfl_xor(c0, off); c1 += __shfl_xor(c1, off);
        c2 += __shfl_xor(c2, off); c3 += __shfl_xor(c3, off);
        c4 += __shfl_xor(c4, off); c5 += __shfl_xor(c5, off);
        c6 += __shfl_xor(c6, off); c7 += __shfl_xor(c7, off);
    }

    const float inv = (s1 > s0) ? 1.f / ssum : 0.f;
    if (lane < 16) {
        float4 o0, o1;
        o0.x = 1.f/(1.f+expf(-c0*inv)); o0.y = 1.f/(1.f+expf(-c1*inv));
        o0.z = 1.f/(1.f+expf(-c2*inv)); o0.w = 1.f/(1.f+expf(-c3*inv));
        o1.x = 1.f/(1.f+expf(-c4*inv)); o1.y = 1.f/(1.f+expf(-c5*inv));
        o1.z = 1.f/(1.f+expf(-c6*inv)); o1.w = 1.f/(1.f+expf(-c7*inv));
        float4* op = (float4*)&out[wid * EMB + lane * 8];
        op[0] = o0;
        op[1] = o1;
    }
}

extern "C" void kernel_launch(void* const* d_in, const int* in_sizes, int n_in,
                              void* d_out, int out_size, void* d_ws, size_t ws_size,
                              hipStream_t stream) {
    const float* emb  = (const float*)d_in[0];   // (20001, 128)
    const int*   edge = (const int*)  d_in[1];   // (640000, 2)
    const float* W    = (const float*)d_in[2];   // (128, 128)
    const float* bsc  = (const float*)d_in[3];   // (128,)
    const float* Watt = (const float*)d_in[4];   // (256,)
    const float* batt = (const float*)d_in[5];   // (1,)
    float* out = (float*)d_out;                  // (20001, 128)

    unsigned short* tab = (unsigned short*)d_ws;            // NSEG*EMB bf16 (5.12 MB)
    float* a_src = (float*)(tab + (size_t)NSEG * EMB);      // NSEG
    float* a_dst = a_src + NSEG;                            // NSEG
    int*   seg_start = (int*)(a_dst + NSEG);                // NSEG+1
    int*   dstc = seg_start + NSEG + 3;                     // NE (compacted dst col)

    prep_kernel<<<SCALE_BLOCKS + BOUNDS_BLOCKS, 256, 0, stream>>>(
        emb, W, bsc, Watt, edge, tab, a_src, a_dst, seg_start, dstc);
    agg_kernel<<<(NSEG + 3) / 4, 256, 0, stream>>>(
        dstc, a_src, a_dst, batt, seg_start, (const unsigned char*)tab, out);
}

// Round 4
// 111.368 us; speedup vs baseline: 1.0640x; 1.0640x over previous
//
#include <hip/hip_runtime.h>
#include <math.h>

#define NSEG 20001      // I_DIM + 1 segments / items
#define EMB  128
#define NE   640000

#define SCALE_BLOCKS 313         // ceil(NSEG/64)
#define BOUNDS_BLOCKS 2500       // NE/256 exact
#define LDSL 129                 // padded row stride (floats): 2-way bank aliasing only

__device__ __forceinline__ float dot4(float4 a, float4 b) {
    return a.x*b.x + a.y*b.y + a.z*b.z + a.w*b.w;
}

#define FMA4(acc, s, b) { acc.x += (s)*(b).x; acc.y += (s)*(b).y; acc.z += (s)*(b).z; acc.w += (s)*(b).w; }

__device__ __forceinline__ unsigned f2bf(float x) {
    unsigned u = __float_as_uint(x);
    return (u + 0x7fffu + ((u >> 16) & 1u)) >> 16;   // round-nearest-even
}

// Fused prep:
//  blocks [0, SCALE_BLOCKS): item_scaled(bf16 tab) + a_src/a_dst.
//    64 rows/block; thread = (cg: 8 cols) x (rg: 4 rows) -> 16 rows/wave.
//    W traffic: 512 B per wave per k for 16 rows = 32 B/row/k (8x less than R3).
//  blocks [SCALE_BLOCKS, +BOUNDS_BLOCKS): segment bounds + dst compaction.
__global__ __launch_bounds__(256) void prep_kernel(
    const float* __restrict__ emb, const float* __restrict__ W,
    const float* __restrict__ bsc, const float* __restrict__ Watt,
    const int* __restrict__ edge,
    unsigned short* __restrict__ tab,       // bf16 item_scaled, NSEG x EMB
    float* __restrict__ a_src, float* __restrict__ a_dst,
    int* __restrict__ seg_start, int* __restrict__ dst)
{
    const int tid = threadIdx.x;
    if (blockIdx.x >= SCALE_BLOCKS) {
        // ---- bounds + dst-compaction ----
        int e = (blockIdx.x - SCALE_BLOCKS) * 256 + tid;
        int2 p = ((const int2*)edge)[e];            // coalesced 8B
        dst[e] = p.y;
        int sp = __shfl_up(p.x, 1);
        if ((tid & 63) == 0) sp = (e == 0) ? -1 : edge[2*e - 2];
        for (int t = sp + 1; t <= p.x; ++t) seg_start[t] = e;
        if (e == NE - 1) {
            for (int t = p.x + 1; t <= NSEG; ++t) seg_start[t] = NE;
        }
        return;
    }

    // ---- scale branch ----
    __shared__ float emb_s[64 * LDSL];   // 33 KB
    const int r0 = blockIdx.x * 64;

    const float4* embg4 = (const float4*)emb;
    const int gmax = NSEG * 32 - 1;
    #pragma unroll
    for (int j = 0; j < 8; ++j) {
        int idx = tid + j * 256;            // 0..2047 tile float4 slots
        int row = idx >> 5, f4 = idx & 31;
        int g = r0 * 32 + idx;
        float4 v = embg4[g <= gmax ? g : gmax];
        float* p = &emb_s[row * LDSL + f4 * 4];
        p[0] = v.x; p[1] = v.y; p[2] = v.z; p[3] = v.w;
    }
    __syncthreads();

    const int cg   = tid & 15;            // cols [8cg, 8cg+8)
    const int rowb = (tid >> 4) * 4;      // 4 rows per thread

    float4 accA[4] = {{0,0,0,0},{0,0,0,0},{0,0,0,0},{0,0,0,0}};
    float4 accB[4] = {{0,0,0,0},{0,0,0,0},{0,0,0,0},{0,0,0,0}};
    const float4* Wg4 = (const float4*)W;

    #pragma unroll 4
    for (int k = 0; k < EMB; ++k) {
        float4 w0 = Wg4[k*32 + cg*2];
        float4 w1 = Wg4[k*32 + cg*2 + 1];
        float a0 = emb_s[(rowb+0)*LDSL + k];
        float a1 = emb_s[(rowb+1)*LDSL + k];
        float a2 = emb_s[(rowb+2)*LDSL + k];
        float a3 = emb_s[(rowb+3)*LDSL + k];
        FMA4(accA[0], a0, w0); FMA4(accB[0], a0, w1);
        FMA4(accA[1], a1, w0); FMA4(accB[1], a1, w1);
        FMA4(accA[2], a2, w0); FMA4(accB[2], a2, w1);
        FMA4(accA[3], a3, w0); FMA4(accB[3], a3, w1);
    }

    const float4 bsA = *(const float4*)&bsc[cg*8];
    const float4 bsB = *(const float4*)&bsc[cg*8 + 4];
    const float4 wsA = *(const float4*)&Watt[cg*8];
    const float4 wsB = *(const float4*)&Watt[cg*8 + 4];
    const float4 wdA = *(const float4*)&Watt[EMB + cg*8];
    const float4 wdB = *(const float4*)&Watt[EMB + cg*8 + 4];

    #pragma unroll
    for (int r = 0; r < 4; ++r) {
        float4 A = accA[r], B = accB[r];
        A.x += bsA.x; A.y += bsA.y; A.z += bsA.z; A.w += bsA.w;
        B.x += bsB.x; B.y += bsB.y; B.z += bsB.z; B.w += bsB.w;
        const int row = r0 + rowb + r;

        if (row < NSEG) {
            uint4 pkt;
            pkt.x = f2bf(A.x) | (f2bf(A.y) << 16);
            pkt.y = f2bf(A.z) | (f2bf(A.w) << 16);
            pkt.z = f2bf(B.x) | (f2bf(B.y) << 16);
            pkt.w = f2bf(B.z) | (f2bf(B.w) << 16);
            ((uint4*)tab)[row * 16 + cg] = pkt;
        }

        float ps = dot4(A, wsA) + dot4(B, wsB);
        float pd = dot4(A, wdA) + dot4(B, wdB);
        #pragma unroll
        for (int off = 8; off >= 1; off >>= 1) {
            ps += __shfl_xor(ps, off);
            pd += __shfl_xor(pd, off);
        }
        if (cg == 0 && row < NSEG) { a_src[row] = ps; a_dst[row] = pd; }
    }
}

__device__ __forceinline__ float bf_lo(unsigned u) { return __uint_as_float(u << 16); }
__device__ __forceinline__ float bf_hi(unsigned u) { return __uint_as_float(u & 0xffff0000u); }
__device__ __forceinline__ float bcastf(float v, int j) {
    return __uint_as_float(__builtin_amdgcn_readlane(__float_as_uint(v), j));
}

// agg: one wave per segment; lane l owns features {2l, 2l+1} (one bf16x2 dword).
// R2 structure (best measured) + unroll-8 for 8 outstanding gathers.
__global__ __launch_bounds__(256) void agg_kernel(
    const int* __restrict__ dst, const float* __restrict__ a_src,
    const float* __restrict__ a_dst, const float* __restrict__ b_att,
    const int* __restrict__ seg_start, const unsigned int* __restrict__ tab32,
    float* __restrict__ out)
{
    const int wid = blockIdx.x * 4 + (threadIdx.x >> 6);
    if (wid >= NSEG) return;                 // wave-uniform exit
    const int lane = threadIdx.x & 63;
    const unsigned int* tabl = tab32 + lane; // row stride 64 dwords

    const int s0 = seg_start[wid];
    const int s1 = seg_start[wid + 1];
    const float aS = a_src[wid] + b_att[0];

    float accx = 0.f, accy = 0.f, ssum = 0.f;

    for (int cb = s0; cb < s1; cb += 64) {
        int n = s1 - cb; if (n > 64) n = 64;
        int e = cb + lane;
        int dmine = 0; float sc = 0.f;
        if (lane < n) {
            dmine = dst[e] << 6;             // pre-scaled dword row offset
            float att = aS + a_dst[dmine >> 6];
            att = att > 0.f ? att : 0.2f * att;   // leaky_relu 0.2
            sc  = expf(att - 1.f);
        }
        ssum += sc;

        int j = 0;
        for (; j + 7 < n; j += 8) {
            float w0 = bcastf(sc, j+0), w1 = bcastf(sc, j+1);
            float w2 = bcastf(sc, j+2), w3 = bcastf(sc, j+3);
            float w4 = bcastf(sc, j+4), w5 = bcastf(sc, j+5);
            float w6 = bcastf(sc, j+6), w7 = bcastf(sc, j+7);
            int d0 = __builtin_amdgcn_readlane(dmine, j+0);
            int d1 = __builtin_amdgcn_readlane(dmine, j+1);
            int d2 = __builtin_amdgcn_readlane(dmine, j+2);
            int d3 = __builtin_amdgcn_readlane(dmine, j+3);
            int d4 = __builtin_amdgcn_readlane(dmine, j+4);
            int d5 = __builtin_amdgcn_readlane(dmine, j+5);
            int d6 = __builtin_amdgcn_readlane(dmine, j+6);
            int d7 = __builtin_amdgcn_readlane(dmine, j+7);
            unsigned u0 = tabl[d0], u1 = tabl[d1], u2 = tabl[d2], u3 = tabl[d3];
            unsigned u4 = tabl[d4], u5 = tabl[d5], u6 = tabl[d6], u7 = tabl[d7];
            accx += w0 * bf_lo(u0); accy += w0 * bf_hi(u0);
            accx += w1 * bf_lo(u1); accy += w1 * bf_hi(u1);
            accx += w2 * bf_lo(u2); accy += w2 * bf_hi(u2);
            accx += w3 * bf_lo(u3); accy += w3 * bf_hi(u3);
            accx += w4 * bf_lo(u4); accy += w4 * bf_hi(u4);
            accx += w5 * bf_lo(u5); accy += w5 * bf_hi(u5);
            accx += w6 * bf_lo(u6); accy += w6 * bf_hi(u6);
            accx += w7 * bf_lo(u7); accy += w7 * bf_hi(u7);
        }
        for (; j < n; ++j) {
            float w = bcastf(sc, j);
            int   d = __builtin_amdgcn_readlane(dmine, j);
            unsigned u = tabl[d];
            accx += w * bf_lo(u);
            accy += w * bf_hi(u);
        }
    }

    #pragma unroll
    for (int off = 32; off >= 1; off >>= 1) ssum += __shfl_xor(ssum, off);

    const float inv = (s1 > s0) ? 1.f / ssum : 0.f;
    float ox = accx * inv, oy = accy * inv;
    ox = 1.f / (1.f + expf(-ox));
    oy = 1.f / (1.f + expf(-oy));
    *(float2*)&out[wid * EMB + 2 * lane] = make_float2(ox, oy);
}

extern "C" void kernel_launch(void* const* d_in, const int* in_sizes, int n_in,
                              void* d_out, int out_size, void* d_ws, size_t ws_size,
                              hipStream_t stream) {
    const float* emb  = (const float*)d_in[0];   // (20001, 128)
    const int*   edge = (const int*)  d_in[1];   // (640000, 2)
    const float* W    = (const float*)d_in[2];   // (128, 128)
    const float* bsc  = (const float*)d_in[3];   // (128,)
    const float* Watt = (const float*)d_in[4];   // (256,)
    const float* batt = (const float*)d_in[5];   // (1,)
    float* out = (float*)d_out;                  // (20001, 128)

    unsigned short* tab = (unsigned short*)d_ws;            // NSEG*EMB bf16 (5.12 MB)
    float* a_src = (float*)(tab + (size_t)NSEG * EMB);      // NSEG
    float* a_dst = a_src + NSEG;                            // NSEG
    int*   seg_start = (int*)(a_dst + NSEG);                // NSEG+1
    int*   dstc = seg_start + NSEG + 3;                     // NE (compacted dst col)

    prep_kernel<<<SCALE_BLOCKS + BOUNDS_BLOCKS, 256, 0, stream>>>(
        emb, W, bsc, Watt, edge, tab, a_src, a_dst, seg_start, dstc);
    agg_kernel<<<(NSEG + 3) / 4, 256, 0, stream>>>(
        dstc, a_src, a_dst, batt, seg_start, (const unsigned int*)tab, out);
}